// Round 6
// baseline (1433.378 us; speedup 1.0000x reference)
//
#include <hip/hip_runtime.h>
#include <math.h>

#define BB 4
#define SS 1024
#define HH 1024
#define LL 4
#define NHH 16
#define NKV 8
#define HD 64
#define FF 3072
#define WW 12
#define NEG_INF (-1e9f)

// wbf (bf16 weight^T buffer) element offsets; OQ..OV are contiguous => merged qkv Bt
#define OQ  0
#define OK_ 1048576
#define OV  1572864
#define OO  2097152
#define OG  3145728
#define OU  6291456
#define OD  9437184

typedef __attribute__((ext_vector_type(8))) short bf16x8;
typedef __attribute__((ext_vector_type(4))) float f32x4;
typedef __attribute__((ext_vector_type(16))) float f32x16;
typedef __attribute__((ext_vector_type(8))) unsigned short u16x8;

__device__ __forceinline__ unsigned short f2bf(float f) {
    union { float f; unsigned int u; } v; v.f = f;
    unsigned int r = (v.u + 0x7fffu + ((v.u >> 16) & 1u)) >> 16;
    return (unsigned short)r;
}
__device__ __forceinline__ float bf2f(unsigned short u) {
    union { unsigned int u; float f; } v; v.u = ((unsigned int)u) << 16;
    return v.f;
}
__device__ __forceinline__ unsigned int pkbf(float lo, float hi) {
    return (unsigned int)f2bf(lo) | ((unsigned int)f2bf(hi) << 16);
}
__device__ __forceinline__ void gll16(const void* g, void* l) {
    __builtin_amdgcn_global_load_lds((const __attribute__((address_space(1))) void*)g,
                                     (__attribute__((address_space(3))) void*)l, 16, 0, 0);
}

// ---------------------------------------------------------------------------
__global__ __launch_bounds__(256) void k_embed(const int* __restrict__ ids,
                                               const float* __restrict__ embed,
                                               float* __restrict__ h) {
    int row = blockIdx.x, tid = threadIdx.x;
    int id = ids[row];
    ((float4*)(h + (size_t)row * HH))[tid] = ((const float4*)(embed + (size_t)id * HH))[tid];
}

// ---------------------------------------------------------------------------
__global__ __launch_bounds__(256) void k_rms_bf16(const float* __restrict__ in,
                                                  const float* __restrict__ w,
                                                  unsigned short* __restrict__ out) {
    __shared__ float red[4];
    int row = blockIdx.x, tid = threadIdx.x;
    float4 v = ((const float4*)(in + (size_t)row * HH))[tid];
    float ss = v.x * v.x + v.y * v.y + v.z * v.z + v.w * v.w;
#pragma unroll
    for (int off = 1; off < 64; off <<= 1) ss += __shfl_xor(ss, off);
    if ((tid & 63) == 0) red[tid >> 6] = ss;
    __syncthreads();
    float tot = red[0] + red[1] + red[2] + red[3];
    float scale = rsqrtf(tot * (1.0f / HH) + 1e-6f);
    float4 wv = ((const float4*)w)[tid];
    ushort4 o;
    o.x = f2bf(v.x * scale * wv.x); o.y = f2bf(v.y * scale * wv.y);
    o.z = f2bf(v.z * scale * wv.z); o.w = f2bf(v.w * scale * wv.w);
    *(ushort4*)&out[(size_t)row * HH + tid * 4] = o;
}

// ---------------------------------------------------------------------------
// Fused: h += p0(+p1(+p2)); then RMSNorm(h)*w -> outx (bf16 or f32).
template <int NP, int BF16OUT>
__global__ __launch_bounds__(256) void k_rms_add(float* __restrict__ h,
                                                 const float* __restrict__ p0,
                                                 const float* __restrict__ p1,
                                                 const float* __restrict__ p2,
                                                 const float* __restrict__ w,
                                                 void* __restrict__ outx) {
    __shared__ float red[4];
    int row = blockIdx.x, tid = threadIdx.x;
    size_t base = (size_t)row * HH;
    float4 v = ((const float4*)(h + base))[tid];
    float4 a = ((const float4*)(p0 + base))[tid];
    v.x += a.x; v.y += a.y; v.z += a.z; v.w += a.w;
    if (NP > 1) {
        float4 b = ((const float4*)(p1 + base))[tid];
        v.x += b.x; v.y += b.y; v.z += b.z; v.w += b.w;
    }
    if (NP > 2) {
        float4 c = ((const float4*)(p2 + base))[tid];
        v.x += c.x; v.y += c.y; v.z += c.z; v.w += c.w;
    }
    ((float4*)(h + base))[tid] = v;
    float ss = v.x * v.x + v.y * v.y + v.z * v.z + v.w * v.w;
#pragma unroll
    for (int off = 1; off < 64; off <<= 1) ss += __shfl_xor(ss, off);
    if ((tid & 63) == 0) red[tid >> 6] = ss;
    __syncthreads();
    float tot = red[0] + red[1] + red[2] + red[3];
    float scale = rsqrtf(tot * (1.0f / HH) + 1e-6f);
    float4 wv = ((const float4*)w)[tid];
    float rx = v.x * scale * wv.x, ry = v.y * scale * wv.y;
    float rz = v.z * scale * wv.z, rw = v.w * scale * wv.w;
    if (BF16OUT) {
        ushort4 o;
        o.x = f2bf(rx); o.y = f2bf(ry); o.z = f2bf(rz); o.w = f2bf(rw);
        *(ushort4*)&((unsigned short*)outx)[base + tid * 4] = o;
    } else {
        float4 o; o.x = rx; o.y = ry; o.z = rz; o.w = rw;
        ((float4*)((float*)outx + base))[tid] = o;
    }
}

// ---------------------------------------------------------------------------
// All 7 weight cast+transposes for one layer in one dispatch (3072 tiles).
__global__ __launch_bounds__(256) void k_cast_all(const float* __restrict__ wq,
                                                  const float* __restrict__ wk,
                                                  const float* __restrict__ wv,
                                                  const float* __restrict__ wo,
                                                  const float* __restrict__ wg,
                                                  const float* __restrict__ wu,
                                                  const float* __restrict__ wd,
                                                  unsigned short* __restrict__ wbf) {
    __shared__ float t[64][65];
    int tI = blockIdx.x;
    const float* W; unsigned short* Wt; int N, K, local;
    if (tI < 256)       { W = wq; Wt = wbf + OQ;  N = 1024; K = 1024; local = tI; }
    else if (tI < 384)  { W = wk; Wt = wbf + OK_; N = 512;  K = 1024; local = tI - 256; }
    else if (tI < 512)  { W = wv; Wt = wbf + OV;  N = 512;  K = 1024; local = tI - 384; }
    else if (tI < 768)  { W = wo; Wt = wbf + OO;  N = 1024; K = 1024; local = tI - 512; }
    else if (tI < 1536) { W = wg; Wt = wbf + OG;  N = 3072; K = 1024; local = tI - 768; }
    else if (tI < 2304) { W = wu; Wt = wbf + OU;  N = 3072; K = 1024; local = tI - 1536; }
    else                { W = wd; Wt = wbf + OD;  N = 1024; K = 3072; local = tI - 2304; }
    int tn = N >> 6;
    int n0 = (local % tn) * 64, k0 = (local / tn) * 64;
    int tid = threadIdx.x;
    int r = tid >> 4;
    int c4 = (tid & 15) * 4;
#pragma unroll
    for (int e = 0; e < 4; ++e) {
        int kk = r + e * 16;
        float4 vv = *(const float4*)&W[(size_t)(k0 + kk) * N + n0 + c4];
        t[c4 + 0][kk] = vv.x;
        t[c4 + 1][kk] = vv.y;
        t[c4 + 2][kk] = vv.z;
        t[c4 + 3][kk] = vv.w;
    }
    __syncthreads();
#pragma unroll
    for (int e = 0; e < 4; ++e) {
        int nn = r + e * 16;
        ushort4 o;
        o.x = f2bf(t[nn][c4 + 0]);
        o.y = f2bf(t[nn][c4 + 1]);
        o.z = f2bf(t[nn][c4 + 2]);
        o.w = f2bf(t[nn][c4 + 3]);
        *(ushort4*)&Wt[(size_t)(n0 + nn) * K + k0 + c4] = o;
    }
}

// ---------------------------------------------------------------------------
// bf16 MFMA GEMM core — 2-phase double-buffered (T3-min): stage(t+1) issued
// BEFORE compute(t); single implicit vmcnt(0)+barrier per K-step.
// EPI: 0 = store f32, 1 = += f32, 2 = store bf16.
template <int EPI>
__device__ __forceinline__ void mgemm_core(const unsigned short* __restrict__ A,
                                           const unsigned short* __restrict__ Bt,
                                           void* __restrict__ Cv,
                                           int N, int K, int lda, int ldb,
                                           int bm, int bn) {
    __shared__ unsigned short As[2][128 * 32];
    __shared__ unsigned short Bs[2][128 * 32];
    int tid = threadIdx.x;
    int w = tid >> 6, l = tid & 63;
    int wr = (w >> 1) * 64, wc = (w & 1) * 64;

    f32x4 acc[4][4] = {};

    // per-lane global row/k-chunk pieces (c = chunk index 0..511)
#define MG_STAGE(s, k0)                                                               \
    {                                                                                 \
        _Pragma("unroll")                                                             \
        for (int i = 0; i < 2; ++i) {                                                 \
            int cb = i * 256 + w * 64;                                                \
            int c = cb + l;                                                           \
            const unsigned short* ga = A + (size_t)(bm + (c >> 2)) * lda + (k0) + (c & 3) * 8; \
            const unsigned short* gb = Bt + (size_t)(bn + (c >> 2)) * ldb + (k0) + (c & 3) * 8; \
            gll16(ga, &As[s][cb * 8]);                                                \
            gll16(gb, &Bs[s][cb * 8]);                                                \
        }                                                                             \
    }

    MG_STAGE(0, 0);
    __syncthreads();

    int nt = K >> 5;
    for (int t = 0; t < nt; ++t) {
        int cur = t & 1;
        if (t + 1 < nt) MG_STAGE(cur ^ 1, (t + 1) * 32);

        bf16x8 af[4], bfr[4];
#pragma unroll
        for (int i = 0; i < 4; ++i) {
            int m = wr + i * 16 + (l & 15);
            af[i] = *(const bf16x8*)&As[cur][m * 32 + (l >> 4) * 8];
            int n = wc + i * 16 + (l & 15);
            bfr[i] = *(const bf16x8*)&Bs[cur][n * 32 + (l >> 4) * 8];
        }
#pragma unroll
        for (int i = 0; i < 4; ++i)
#pragma unroll
            for (int j = 0; j < 4; ++j)
                acc[i][j] = __builtin_amdgcn_mfma_f32_16x16x32_bf16(af[i], bfr[j], acc[i][j], 0, 0, 0);
        __syncthreads();
    }
#undef MG_STAGE

#pragma unroll
    for (int i = 0; i < 4; ++i) {
        int rbase = bm + wr + i * 16 + (l >> 4) * 4;
#pragma unroll
        for (int j = 0; j < 4; ++j) {
            int col = bn + wc + j * 16 + (l & 15);
#pragma unroll
            for (int r = 0; r < 4; ++r) {
                size_t off = (size_t)(rbase + r) * N + col;
                if (EPI == 0) ((float*)Cv)[off] = acc[i][j][r];
                else if (EPI == 1) ((float*)Cv)[off] += acc[i][j][r];
                else ((unsigned short*)Cv)[off] = f2bf(acc[i][j][r]);
            }
        }
    }
}

// Split-K GEMM: blockIdx.z = part; partial f32 -> p0/p1/p2.
template <int PARTS>
__global__ __launch_bounds__(256) void k_mgemm_splitk(const unsigned short* __restrict__ A,
                                                      const unsigned short* __restrict__ Bt,
                                                      float* __restrict__ p0,
                                                      float* __restrict__ p1,
                                                      float* __restrict__ p2,
                                                      int N, int Ktot, int lda) {
    int part = blockIdx.z;
    int Kp = Ktot / PARTS;
    float* C = (part == 0) ? p0 : (part == 1 ? p1 : p2);
    mgemm_core<0>(A + part * Kp, Bt + part * Kp, C, N, Kp, lda, Ktot,
                  blockIdx.y * 128, blockIdx.x * 128);
}

__global__ __launch_bounds__(256) void k_mgemm_gu(const unsigned short* __restrict__ A,
                                                  const unsigned short* __restrict__ wgt,
                                                  const unsigned short* __restrict__ wut,
                                                  unsigned short* __restrict__ g,
                                                  unsigned short* __restrict__ u) {
    int nt = blockIdx.x;
    const unsigned short* Bt = (nt < 24) ? wgt : wut;
    unsigned short* C = (nt < 24) ? g : u;
    int bn = (nt < 24 ? nt : nt - 24) * 128;
    mgemm_core<2>(A, Bt, C, 3072, 1024, 1024, 1024, blockIdx.y * 128, bn);
}

// ---------------------------------------------------------------------------
// Per-head RMSNorm + RoPE; input = p0+p1 (qkv split-K partials, row stride 2048),
// output dense bf16 [rows][nheads*64].
__global__ __launch_bounds__(256) void k_qknorm_rope(const float* __restrict__ p0,
                                                     const float* __restrict__ p1,
                                                     unsigned short* __restrict__ out,
                                                     const float* __restrict__ nw,
                                                     int nheads, int coloff) {
    int tid = threadIdx.x;
    int w = tid >> 6, lane = tid & 63;
    int gid = blockIdx.x * 4 + w;
    int row = gid / nheads;
    int head = gid - row * nheads;
    int pos = row & (SS - 1);
    size_t src = (size_t)row * 2048 + coloff + head * 64 + lane;
    float xv = p0[src] + p1[src];
    float ss = xv * xv;
#pragma unroll
    for (int off = 1; off < 64; off <<= 1) ss += __shfl_xor(ss, off);
    float scale = rsqrtf(ss * (1.0f / HD) + 1e-6f);
    float xn = xv * scale * nw[lane];
    int j = lane & 31;
    float inv_freq = powf(1.0e6f, -(float)j * (1.0f / 32.0f));
    float f = (float)pos * inv_freq;
    float c = cosf(f), s = sinf(f);
    float partner = __shfl_xor(xn, 32);
    float rot = (lane < 32) ? -partner : partner;
    out[(size_t)gid * HD + lane] = f2bf(xn * c + rot * s);
}

// V reduce+cast: vbf[row][c] = bf16(p0+p1) from cols 1536..2047.
__global__ __launch_bounds__(256) void k_vred(const float* __restrict__ p0,
                                              const float* __restrict__ p1,
                                              unsigned short* __restrict__ v) {
    int i = blockIdx.x * 256 + threadIdx.x;
    int row = i >> 6;
    int c = (i & 63) * 8;
    size_t base = (size_t)row * 2048 + 1536 + c;
    float4 a0 = *(const float4*)&p0[base], a1 = *(const float4*)&p0[base + 4];
    float4 b0 = *(const float4*)&p1[base], b1 = *(const float4*)&p1[base + 4];
    u16x8 o;
    o[0] = f2bf(a0.x + b0.x); o[1] = f2bf(a0.y + b0.y);
    o[2] = f2bf(a0.z + b0.z); o[3] = f2bf(a0.w + b0.w);
    o[4] = f2bf(a1.x + b1.x); o[5] = f2bf(a1.y + b1.y);
    o[6] = f2bf(a1.z + b1.z); o[7] = f2bf(a1.w + b1.w);
    *(u16x8*)&v[(size_t)row * 512 + c] = o;
}

// ---------------------------------------------------------------------------
// MFMA flash attention (unchanged from round 4).
__global__ __launch_bounds__(256) void k_mattn(const unsigned short* __restrict__ q,
                                               const unsigned short* __restrict__ k,
                                               const unsigned short* __restrict__ v,
                                               const int* __restrict__ amask,
                                               unsigned short* __restrict__ out,
                                               int sliding) {
    __shared__ __align__(16) char smem[18432];
    unsigned short* Klds = (unsigned short*)smem;
    unsigned int*   VtU  = (unsigned int*)(smem + 8192);
    float* mlds          = (float*)(smem + 17152);
    unsigned short* Olds = (unsigned short*)smem;

    const int b = blockIdx.z, head = blockIdx.y, q0 = blockIdx.x * 128;
    const int kvh = head >> 1;
    const int tid = threadIdx.x, w = tid >> 6, lane = tid & 63;
    const int h = lane >> 5, ln31 = lane & 31;
    const int qg = q0 + w * 32 + ln31;
    const float sscale = 0.125f;

    bf16x8 qf[4];
    const unsigned short* qrow = q + (size_t)(b * SS + qg) * 1024 + head * 64;
#pragma unroll
    for (int c = 0; c < 4; ++c) qf[c] = *(const bf16x8*)(qrow + c * 16 + h * 8);

    f32x16 O0 = {}, O1 = {};
    float m = -3.4e38f, l_sum = 0.0f;

    int t_lo = 0, t_hi = (SS >> 6) - 1;
    if (sliding) {
        int lo = q0 - WW; if (lo < 0) lo = 0;
        int hi = q0 + 127 + WW; if (hi > SS - 1) hi = SS - 1;
        t_lo = lo >> 6; t_hi = hi >> 6;
    }

    const int vd = tid & 63, vw = tid >> 6;

    for (int t = t_lo; t <= t_hi; ++t) {
        int kv0 = t << 6;
        __syncthreads();
        if (tid < 64) mlds[tid] = amask[b * SS + kv0 + tid] ? 0.0f : NEG_INF;
#pragma unroll
        for (int i = 0; i < 2; ++i) {
            int slot = i * 256 + w * 64 + lane;
            int row = slot >> 3, u = slot & 7;
            int ug = u ^ (row & 7);
            const unsigned short* src = k + (size_t)(b * SS + kv0 + row) * 512 + kvh * 64 + ug * 8;
            gll16(src, Klds + (size_t)slot * 8);
        }
        {
            const unsigned short* vsrc = v + (size_t)(b * SS + kv0 + vw * 16) * 512 + kvh * 64 + vd;
            unsigned short tmp[16];
#pragma unroll
            for (int kk = 0; kk < 16; ++kk) tmp[kk] = vsrc[(size_t)kk * 512];
#pragma unroll
            for (int j = 0; j < 8; ++j)
                VtU[vd * 35 + vw * 8 + j] =
                    (unsigned int)tmp[2 * j] | ((unsigned int)tmp[2 * j + 1] << 16);
        }
        __syncthreads();

        f32x16 a0 = {}, a1 = {};
#pragma unroll
        for (int c = 0; c < 4; ++c) {
            int u = (2 * c + h) ^ (ln31 & 7);
            bf16x8 k0 = *(const bf16x8*)&Klds[ln31 * 64 + u * 8];
            bf16x8 k1 = *(const bf16x8*)&Klds[(32 + ln31) * 64 + u * 8];
            a0 = __builtin_amdgcn_mfma_f32_32x32x16_bf16(k0, qf[c], a0, 0, 0, 0);
            a1 = __builtin_amdgcn_mfma_f32_32x32x16_bf16(k1, qf[c], a1, 0, 0, 0);
        }

        float tmax = -3.4e38f;
#pragma unroll
        for (int r = 0; r < 16; ++r) {
            int kl = (r & 3) + 8 * (r >> 2) + 4 * h;
            float mv0 = mlds[kl], mv1 = mlds[32 + kl];
            if (sliding) {
                int d0 = qg - (kv0 + kl); if (d0 < 0) d0 = -d0;
                int d1 = qg - (kv0 + 32 + kl); if (d1 < 0) d1 = -d1;
                if (d0 > WW) mv0 = NEG_INF;
                if (d1 > WW) mv1 = NEG_INF;
            }
            a0[r] = a0[r] * sscale + mv0;
            a1[r] = a1[r] * sscale + mv1;
            tmax = fmaxf(tmax, fmaxf(a0[r], a1[r]));
        }
        tmax = fmaxf(tmax, __shfl_xor(tmax, 32));
        float nm = fmaxf(m, tmax);
        float corr = __expf(m - nm);
        float tsum = 0.0f;
#pragma unroll
        for (int r = 0; r < 16; ++r) {
            a0[r] = __expf(a0[r] - nm);
            a1[r] = __expf(a1[r] - nm);
            tsum += a0[r] + a1[r];
        }
        tsum += __shfl_xor(tsum, 32);
        l_sum = l_sum * corr + tsum;
#pragma unroll
        for (int r = 0; r < 16; ++r) { O0[r] *= corr; O1[r] *= corr; }
        m = nm;

#pragma unroll
        for (int s = 0; s < 2; ++s) {
#pragma unroll
            for (int c2 = 0; c2 < 2; ++c2) {
                float p0v = s ? a1[8 * c2 + 0] : a0[8 * c2 + 0];
                float p1v = s ? a1[8 * c2 + 1] : a0[8 * c2 + 1];
                float p2v = s ? a1[8 * c2 + 2] : a0[8 * c2 + 2];
                float p3v = s ? a1[8 * c2 + 3] : a0[8 * c2 + 3];
                float p4v = s ? a1[8 * c2 + 4] : a0[8 * c2 + 4];
                float p5v = s ? a1[8 * c2 + 5] : a0[8 * c2 + 5];
                float p6v = s ? a1[8 * c2 + 6] : a0[8 * c2 + 6];
                float p7v = s ? a1[8 * c2 + 7] : a0[8 * c2 + 7];
                unsigned int A0 = pkbf(p0v, p1v);
                unsigned int A1 = pkbf(p2v, p3v);
                unsigned int A2 = pkbf(p4v, p5v);
                unsigned int A3 = pkbf(p6v, p7v);
                unsigned int pA0 = (unsigned int)__shfl_xor((int)A0, 32);
                unsigned int pA1 = (unsigned int)__shfl_xor((int)A1, 32);
                unsigned int pA2 = (unsigned int)__shfl_xor((int)A2, 32);
                unsigned int pA3 = (unsigned int)__shfl_xor((int)A3, 32);
                union { unsigned int u[4]; bf16x8 v; } pf;
                pf.u[0] = h ? pA2 : A0;
                pf.u[1] = h ? pA3 : A1;
                pf.u[2] = h ? A2 : pA0;
                pf.u[3] = h ? A3 : pA1;
#pragma unroll
                for (int dt = 0; dt < 2; ++dt) {
                    int base = (dt * 32 + ln31) * 35 + s * 16 + c2 * 8 + h * 4;
                    union { unsigned int u[4]; bf16x8 v; } vf;
                    vf.u[0] = VtU[base + 0];
                    vf.u[1] = VtU[base + 1];
                    vf.u[2] = VtU[base + 2];
                    vf.u[3] = VtU[base + 3];
                    if (dt == 0) O0 = __builtin_amdgcn_mfma_f32_32x32x16_bf16(vf.v, pf.v, O0, 0, 0, 0);
                    else         O1 = __builtin_amdgcn_mfma_f32_32x32x16_bf16(vf.v, pf.v, O1, 0, 0, 0);
                }
            }
        }
    }

    __syncthreads();
    float rl = 1.0f / l_sum;
    unsigned short* myO = Olds + w * 2240;
#pragma unroll
    for (int dt = 0; dt < 2; ++dt)
#pragma unroll
        for (int r = 0; r < 16; ++r) {
            int d = dt * 32 + (r & 3) + 8 * (r >> 2) + 4 * h;
            float val = (dt ? O1[r] : O0[r]) * rl;
            myO[ln31 * 70 + d] = f2bf(val);
        }
    int qr = lane >> 1, half = lane & 1;
    const unsigned int* osrc = (const unsigned int*)Olds + (size_t)w * 1120 + qr * 35 + half * 16;
    unsigned int vals[16];
#pragma unroll
    for (int j = 0; j < 16; ++j) vals[j] = osrc[j];
    unsigned short* dst = out + (size_t)(b * SS + q0 + w * 32 + qr) * 1024 + head * 64 + half * 32;
#pragma unroll
    for (int j = 0; j < 4; ++j)
        ((uint4*)dst)[j] = make_uint4(vals[4 * j], vals[4 * j + 1], vals[4 * j + 2], vals[4 * j + 3]);
}

// ---------------------------------------------------------------------------
__global__ __launch_bounds__(256) void k_silu_bf16(unsigned short* __restrict__ g,
                                                   const unsigned short* __restrict__ u) {
    int i = blockIdx.x * 256 + threadIdx.x;
    u16x8 gv = ((const u16x8*)g)[i];
    u16x8 uv = ((const u16x8*)u)[i];
    u16x8 o;
#pragma unroll
    for (int j = 0; j < 8; ++j) {
        float gf = bf2f(gv[j]), uf = bf2f(uv[j]);
        o[j] = f2bf(gf / (1.0f + __expf(-gf)) * uf);
    }
    ((u16x8*)g)[i] = o;
}

// ---------------------------------------------------------------------------
extern "C" void kernel_launch(void* const* d_in, const int* in_sizes, int n_in,
                              void* d_out, int out_size, void* d_ws, size_t ws_size,
                              hipStream_t stream) {
    const int* input_ids = (const int*)d_in[0];
    const int* amask     = (const int*)d_in[1];
    const float* embed   = (const float*)d_in[2];
    const float* wq      = (const float*)d_in[3];
    const float* wk      = (const float*)d_in[4];
    const float* wv      = (const float*)d_in[5];
    const float* wo      = (const float*)d_in[6];
    const float* qnw     = (const float*)d_in[7];
    const float* knw     = (const float*)d_in[8];
    const float* ln1     = (const float*)d_in[9];
    const float* ln2     = (const float*)d_in[10];
    const float* wg      = (const float*)d_in[11];
    const float* wu      = (const float*)d_in[12];
    const float* wd      = (const float*)d_in[13];
    const float* fnorm   = (const float*)d_in[14];
    float* out = (float*)d_out;

    const int ROWS = BB * SS;  // 4096
    float* h = (float*)d_ws;                                // [4096,1024] f32, 16MB
    unsigned short* xb  = (unsigned short*)(h + (size_t)ROWS * HH);   // [4096,1024] bf16
    unsigned short* qbf = xb + (size_t)ROWS * HH;           // [4096,1024]
    unsigned short* kbf = qbf + (size_t)ROWS * HH;          // [4096,512]
    unsigned short* vbf = kbf + (size_t)ROWS * (NKV * HD);  // [4096,512]
    unsigned short* gbf = vbf + (size_t)ROWS * (NKV * HD);  // [4096,3072]
    unsigned short* ubf = gbf + (size_t)ROWS * FF;          // [4096,3072]
    unsigned short* wbf = ubf + (size_t)ROWS * FF;          // 12.58M elems
    float* P0 = (float*)(wbf + 12582912);                   // [4096,2048] f32, 32MB
    float* P1 = P0 + (size_t)ROWS * 2048;                   // [4096,2048] f32, 32MB

    k_embed<<<ROWS, 256, 0, stream>>>(input_ids, embed, h);
    k_rms_bf16<<<ROWS, 256, 0, stream>>>(h, ln1, xb);

    for (int l = 0; l < LL; ++l) {
        const float* wq_l = wq + (size_t)l * HH * (NHH * HD);
        const float* wk_l = wk + (size_t)l * HH * (NKV * HD);
        const float* wv_l = wv + (size_t)l * HH * (NKV * HD);
        const float* wo_l = wo + (size_t)l * (NHH * HD) * HH;
        const float* wg_l = wg + (size_t)l * HH * FF;
        const float* wu_l = wu + (size_t)l * HH * FF;
        const float* wd_l = wd + (size_t)l * FF * HH;

        k_cast_all<<<3072, 256, 0, stream>>>(wq_l, wk_l, wv_l, wo_l, wg_l, wu_l, wd_l, wbf);

        // merged QKV (N=2048, contiguous wq|wk|wv in wbf), split-K=2 -> P0,P1
        k_mgemm_splitk<2><<<dim3(16, 32, 2), 256, 0, stream>>>(xb, wbf + OQ, P0, P1,
                                                               nullptr, 2048, 1024, 1024);

        k_qknorm_rope<<<ROWS * NHH / 4, 256, 0, stream>>>(P0, P1, qbf, qnw + l * HD, NHH, 0);
        k_qknorm_rope<<<ROWS * NKV / 4, 256, 0, stream>>>(P0, P1, kbf, knw + l * HD, NKV, 1024);
        k_vred<<<ROWS * 512 / 8 / 256, 256, 0, stream>>>(P0, P1, vbf);

        k_mattn<<<dim3(SS / 128, NHH, BB), 256, 0, stream>>>(qbf, kbf, vbf, amask, xb, l & 1);

        // wo: split-K=2 -> P0,P1 (dense [4096][1024]); fused reduce + ln2-RMS.
        k_mgemm_splitk<2><<<dim3(8, 32, 2), 256, 0, stream>>>(xb, wbf + OO, P0, P1,
                                                              nullptr, 1024, 1024, 1024);
        k_rms_add<2, 1><<<ROWS, 256, 0, stream>>>(h, P0, P1, nullptr, ln2 + l * HH, xb);

        k_mgemm_gu<<<dim3(48, 32), 256, 0, stream>>>(xb, wbf + OG, wbf + OU, gbf, ubf);

        k_silu_bf16<<<ROWS * FF / 8 / 256, 256, 0, stream>>>(gbf, ubf);

        // wd: split-K=3 -> P0,P1,(float*)wbf (overwrites OQ area; recast next layer).
        k_mgemm_splitk<3><<<dim3(8, 32, 3), 256, 0, stream>>>(gbf, wbf + OD, P0, P1,
                                                              (float*)wbf, 1024, 3072, 3072);
        if (l < LL - 1) {
            k_rms_add<3, 1><<<ROWS, 256, 0, stream>>>(h, P0, P1, (float*)wbf,
                                                      ln1 + (l + 1) * HH, xb);
        } else {
            k_rms_add<3, 0><<<ROWS, 256, 0, stream>>>(h, P0, P1, (float*)wbf,
                                                      fnorm, out);
        }
    }
}